// Round 1
// baseline (42068.195 us; speedup 1.0000x reference)
//
#include <hip/hip_runtime.h>
#include <math.h>

// ChaoticLSTM (Lee-oscillator LSTM) on MI355X.
// BS=64, S=512, I=256, H=512, fp32. out = [output(64*512*512) | ht(64*512) | ct(64*512)].
//
// Persistent cooperative kernel: 256 blocks x 512 threads, one block per CU.
// Block b owns h-dims {2b, 2b+1} for ALL 64 samples; cell state c lives in
// registers (threads 0..127). h_t is exchanged via d_out (written anyway).
// Custom per-step grid barrier with per-step counters in ws (zeroed by a
// prologue kernel -> no dependence on ws poison value).

#define NB   256
#define BT   512
#define BSZ  64
#define SEQ  512
#define INP  256
#define HID  512
#define GAT  2048          // 4*HID
#define KTOT 768           // INP+HID
#define OUT_MAIN (BSZ*SEQ*HID)

// ---------------- fast activations -------------------------------------
__device__ __forceinline__ float rcp_f(float a) { return __builtin_amdgcn_rcpf(a); }
__device__ __forceinline__ float sigm_f(float a) {
    return rcp_f(1.0f + __expf(-a));
}
__device__ __forceinline__ float tanh_f(float a) {
    // 1 - 2/(e^{2a}+1); saturates correctly for |a| large (exp->0 or inf)
    return 1.0f - 2.0f * rcp_f(__expf(2.0f * a) + 1.0f);
}

// Lee oscillator: z_N after 25 iters; u=v=z=0 start.
// u1 = f(0.6u+0.6v-0.5z+0.5x); v1 = f(-0.6u-0.6v-0.5z+0.5x);
// z1 = (u1-v1)*exp(-50x^2) + f(x)
template <bool TANH>
__device__ __forceinline__ float lee(float xg) {
    float w   = TANH ? tanh_f(xg) : sigm_f(xg);
    float dec = __expf(-50.0f * xg * xg);
    float hx  = 0.5f * xg;
    float u = 0.0f, v = 0.0f, z = 0.0f;
#pragma unroll
    for (int i = 0; i < 25; ++i) {
        float tz = fmaf(-0.5f, z, hx);
        float s6 = 0.6f * (u + v);
        float au = tz + s6;
        float av = tz - s6;
        u = TANH ? tanh_f(au) : sigm_f(au);
        v = TANH ? tanh_f(av) : sigm_f(av);
        z = fmaf(u - v, dec, w);
    }
    return z;
}

// ---------------- grid barrier helpers ----------------------------------
__device__ __forceinline__ void bar_arrive(unsigned* ctr, int slot) {
    // caller must __syncthreads() first so all block writes are issued
    if (threadIdx.x == 0) {
        __threadfence();
        __hip_atomic_fetch_add(ctr + slot, 1u, __ATOMIC_RELEASE, __HIP_MEMORY_SCOPE_AGENT);
    }
}
__device__ __forceinline__ void bar_wait(unsigned* ctr, int slot) {
    if (threadIdx.x == 0) {
        while (__hip_atomic_load(ctr + slot, __ATOMIC_ACQUIRE, __HIP_MEMORY_SCOPE_AGENT) <
               (unsigned)NB) {
            __builtin_amdgcn_s_sleep(2);
        }
    }
    __syncthreads();
    __threadfence();
}

__device__ __forceinline__ void fma8(const float4& w, const float4& a, const float4& b,
                                     float& A, float& B) {
    A = fmaf(w.x, a.x, A); A = fmaf(w.y, a.y, A);
    A = fmaf(w.z, a.z, A); A = fmaf(w.w, a.w, A);
    B = fmaf(w.x, b.x, B); B = fmaf(w.y, b.y, B);
    B = fmaf(w.z, b.z, B); B = fmaf(w.w, b.w, B);
}

// ---------------- prologue: zero barrier counters ------------------------
__global__ void zero_ws(unsigned* ctr) { ctr[threadIdx.x] = 0u; }

// ---------------- main persistent kernel --------------------------------
__global__ void __launch_bounds__(BT, 2)
lee_lstm(const float* __restrict__ x,  const float* __restrict__ Wi,
         const float* __restrict__ Wh, const float* __restrict__ bia,
         const float* __restrict__ h0, const float* __restrict__ c0,
         float* __restrict__ out, float* __restrict__ ws) {
    unsigned* ctr = (unsigned*)ws;
    float* Wt = ws + 1024;            // Wt[c][k], c-major, stride KTOT (6.3MB)

    const int tid = threadIdx.x;
    const int bid = blockIdx.x;

    __shared__ float2 red[BT];        // split-K reduction
    __shared__ float  gin[8][64];     // gate pre-activations for this block
    __shared__ float  zl[8][64];      // lee outputs

    // ---- phase 0: transpose+fuse weights: Wt[c][k] = k<INP ? Wi[k][c] : Wh[k-INP][c]
    {
        int g  = bid * BT + tid;      // 0..131071
        int c  = g & (GAT - 1);
        int kb = (g >> 11) * 12;      // 64 k-groups * 12 = 768
        float* dst = Wt + c * KTOT + kb;
#pragma unroll
        for (int j = 0; j < 12; ++j) {
            int k = kb + j;
            dst[j] = (k < INP) ? Wi[k * GAT + c] : Wh[(k - INP) * GAT + c];
        }
    }
    __syncthreads();
    bar_arrive(ctr, 0);
    bar_wait(ctr, 0);                 // Wt ready everywhere

    // ---- per-thread roles
    const int kh = tid >> 8;          // split-K half: 0/1
    const int t8 = tid & 255;
    const int ci = t8 & 7;            // 0..7 -> (gate type, hd parity)
    const int sq = t8 >> 3;           // 0..31 -> samples {sq, sq+32}
    const int gt = ci >> 1;           // 0:i 1:f 2:g 3:o
    const int hdq = 2 * bid + (ci & 1);
    const int col = gt * HID + hdq;
    const float* wrow = Wt + col * KTOT;
    const float bias  = bia[col];
    const int s0 = sq, s1 = sq + 32;

    // update-phase roles (threads 0..127): (hd_i, sample)
    const int uhd_i = tid >> 6;       // 0/1 when tid<128
    const int us    = tid & 63;
    const int uhd   = 2 * bid + uhd_i;
    float creg = 0.0f;
    if (tid < 128) creg = c0[us * HID + uhd];

    float accA = 0.0f, accB = 0.0f;
    // x-part for t=0 (k in [kh*128, kh*128+128))
    {
        const float4* wp = (const float4*)(wrow + kh * 128);
        const float4* xa = (const float4*)(x + s0 * (SEQ * INP) + kh * 128);
        const float4* xb = (const float4*)(x + s1 * (SEQ * INP) + kh * 128);
#pragma unroll 4
        for (int i = 0; i < 32; ++i) fma8(wp[i], xa[i], xb[i], accA, accB);
    }

    for (int t = 0; t < SEQ; ++t) {
        if (t > 0) bar_wait(ctr, t);  // h_{t-1} visible device-wide

        // ---- h-part GEMM (k in [kh*256, kh*256+256) of h)
        {
            const float4* wq = (const float4*)(wrow + INP + kh * 256);
            const float* hA = (t == 0) ? (h0 + s0 * HID)
                                       : (out + s0 * (SEQ * HID) + (t - 1) * HID);
            const float* hB = (t == 0) ? (h0 + s1 * HID)
                                       : (out + s1 * (SEQ * HID) + (t - 1) * HID);
            const float4* ha = (const float4*)(hA + kh * 256);
            const float4* hb = (const float4*)(hB + kh * 256);
#pragma unroll 4
            for (int i = 0; i < 64; ++i) fma8(wq[i], ha[i], hb[i], accA, accB);
        }

        // ---- split-K reduce + bias
        red[tid] = make_float2(accA, accB);
        __syncthreads();
        if (tid < 256) {
            float2 o = red[tid + 256];
            gin[ci][sq]      = accA + o.x + bias;
            gin[ci][sq + 32] = accB + o.y + bias;
        }
        __syncthreads();

        // ---- lee on all 512 gate elements (wave-uniform gate type)
        {
            int lci = tid >> 6;       // 0..7, uniform per wave
            int ls  = tid & 63;
            float gv = gin[lci][ls];
            float zres = (lci == 4 || lci == 5) ? lee<true>(gv) : lee<false>(gv);
            zl[lci][ls] = zres;
        }
        __syncthreads();

        // ---- cell/hidden update (threads 0..127, c in registers)
        if (tid < 128) {
            float iv = zl[0 + uhd_i][us];
            float fv = zl[2 + uhd_i][us];
            float gv = zl[4 + uhd_i][us];
            float ov = zl[6 + uhd_i][us];
            float cn = fmaf(fv, creg, iv * gv);
            creg = cn;
            float hn = ov * lee<true>(cn);
            out[us * (SEQ * HID) + t * HID + uhd] = hn;
            if (t == SEQ - 1) {
                out[OUT_MAIN + us * HID + uhd] = hn;                  // ht
                out[OUT_MAIN + BSZ * HID + us * HID + uhd] = cn;      // ct
            }
        }
        __syncthreads();
        bar_arrive(ctr, t + 1);

        // ---- overlap barrier latency: x@Wi partial for step t+1 (no h dep)
        if (t < SEQ - 1) {
            const float4* wp = (const float4*)(wrow + kh * 128);
            const float4* xa = (const float4*)(x + s0 * (SEQ * INP) + (t + 1) * INP + kh * 128);
            const float4* xb = (const float4*)(x + s1 * (SEQ * INP) + (t + 1) * INP + kh * 128);
            accA = 0.0f; accB = 0.0f;
#pragma unroll 4
            for (int i = 0; i < 32; ++i) fma8(wp[i], xa[i], xb[i], accA, accB);
        }
    }
}

extern "C" void kernel_launch(void* const* d_in, const int* in_sizes, int n_in,
                              void* d_out, int out_size, void* d_ws, size_t ws_size,
                              hipStream_t stream) {
    (void)in_sizes; (void)n_in; (void)out_size; (void)ws_size;
    const float* x  = (const float*)d_in[0];
    const float* Wi = (const float*)d_in[1];
    const float* Wh = (const float*)d_in[2];
    const float* b  = (const float*)d_in[3];
    const float* h0 = (const float*)d_in[4];
    const float* c0 = (const float*)d_in[5];
    float* out = (float*)d_out;
    float* ws  = (float*)d_ws;

    hipLaunchKernelGGL(zero_ws, dim3(1), dim3(1024), 0, stream, (unsigned*)d_ws);

    void* args[8];
    args[0] = (void*)&x;  args[1] = (void*)&Wi; args[2] = (void*)&Wh; args[3] = (void*)&b;
    args[4] = (void*)&h0; args[5] = (void*)&c0; args[6] = (void*)&out; args[7] = (void*)&ws;
    hipLaunchCooperativeKernel(reinterpret_cast<const void*>(lee_lstm),
                               dim3(NB), dim3(BT), args, 0, stream);
}

// Round 2
// 22327.161 us; speedup vs baseline: 1.8842x; 1.8842x over previous
//
#include <hip/hip_runtime.h>
#include <math.h>

// ChaoticLSTM (Lee-oscillator LSTM) on MI355X.
// BS=64, S=512, I=256, H=512, fp32. out = [output(64*512*512) | ht(64*512) | ct(64*512)].
//
// Persistent cooperative kernel: 256 blocks x 512 threads, one block per CU.
// Block b owns h-dims {2b, 2b+1} for ALL 64 samples; cell state c lives in
// registers (threads 0..127). h_t is exchanged via d_out (written anyway).
//
// Round-2 sync protocol (round-1 lost 91% of time to per-step L2 wbl2+inv fences):
//  - h stores are sc0/sc1 WRITE-THROUGH (reach L3 coherence point directly)
//    -> release needs only vmcnt drain + relaxed agent atomic, NO buffer_wbl2.
//  - two-level arrival: 32-wide group counters (8 padded lines) -> 1 global ctr.
//  - waiters poll global ctr with relaxed agent loads, then a per-wave
//    acquire fence (buffer_inv only) before touching h.

#define NB   256
#define BT   512
#define BSZ  64
#define SEQ  512
#define INP  256
#define HID  512
#define GAT  2048          // 4*HID
#define KTOT 768           // INP+HID
#define OUT_MAIN (BSZ*SEQ*HID)

#define SLOT_STRIDE 544    // uints per barrier slot (8 grp + 1 glob + pad, 128B each)
#define N_SLOTS     513    // slot 0 = weights ready; slot t+1 = h_t ready
#define CTR_WORDS   (N_SLOTS * SLOT_STRIDE)
#define WT_OFFSET   (1 << 19)   // floats; 2MB into ws

// ---------------- fast activations -------------------------------------
__device__ __forceinline__ float rcp_f(float a) { return __builtin_amdgcn_rcpf(a); }
__device__ __forceinline__ float sigm_f(float a) {
    return rcp_f(1.0f + __expf(-a));
}
__device__ __forceinline__ float tanh_f(float a) {
    return 1.0f - 2.0f * rcp_f(__expf(2.0f * a) + 1.0f);
}

template <bool TANH>
__device__ __forceinline__ float lee(float xg) {
    float w   = TANH ? tanh_f(xg) : sigm_f(xg);
    float dec = __expf(-50.0f * xg * xg);
    float hx  = 0.5f * xg;
    float u = 0.0f, v = 0.0f, z = 0.0f;
#pragma unroll
    for (int i = 0; i < 25; ++i) {
        float tz = fmaf(-0.5f, z, hx);
        float s6 = 0.6f * (u + v);
        float au = tz + s6;
        float av = tz - s6;
        u = TANH ? tanh_f(au) : sigm_f(au);
        v = TANH ? tanh_f(av) : sigm_f(av);
        z = fmaf(u - v, dec, w);
    }
    return z;
}

// ---------------- sc0/sc1 write-through store ---------------------------
__device__ __forceinline__ void st_f32_sc(float* p, float v) {
    asm volatile("global_store_dword %0, %1, off sc0 sc1" :: "v"(p), "v"(v) : "memory");
}

// ---------------- two-level grid barrier --------------------------------
// arrive: drain own stores, bump group ctr; group-last bumps global ctr.
__device__ __forceinline__ void bar_arrive(unsigned* ctr, int slot, int g) {
    asm volatile("s_waitcnt vmcnt(0)" ::: "memory");  // per-wave: sc1 stores done
    __syncthreads();                                   // all waves drained
    if (threadIdx.x == 0) {
        unsigned* grp  = ctr + slot * SLOT_STRIDE + g * 32;
        unsigned* glob = ctr + slot * SLOT_STRIDE + 256;
        if (__hip_atomic_fetch_add(grp, 1u, __ATOMIC_RELAXED,
                                   __HIP_MEMORY_SCOPE_AGENT) == 31u)
            __hip_atomic_fetch_add(glob, 1u, __ATOMIC_RELAXED,
                                   __HIP_MEMORY_SCOPE_AGENT);
    }
}
// wait: poll global ctr (relaxed, L2-bypassing), then per-wave acquire fence
// (buffer_inv, no writeback) so cached loads can't see stale lines.
__device__ __forceinline__ void bar_wait(unsigned* ctr, int slot) {
    if (threadIdx.x == 0) {
        unsigned* glob = ctr + slot * SLOT_STRIDE + 256;
        while (__hip_atomic_load(glob, __ATOMIC_RELAXED,
                                 __HIP_MEMORY_SCOPE_AGENT) < 8u)
            __builtin_amdgcn_s_sleep(1);
    }
    __syncthreads();
    __builtin_amdgcn_fence(__ATOMIC_ACQUIRE, "agent");  // per-wave buffer_inv
}

__device__ __forceinline__ void fma8(const float4& w, const float4& a, const float4& b,
                                     float& A, float& B) {
    A = fmaf(w.x, a.x, A); A = fmaf(w.y, a.y, A);
    A = fmaf(w.z, a.z, A); A = fmaf(w.w, a.w, A);
    B = fmaf(w.x, b.x, B); B = fmaf(w.y, b.y, B);
    B = fmaf(w.z, b.z, B); B = fmaf(w.w, b.w, B);
}

// ---------------- prologue: zero barrier counters ------------------------
__global__ void zero_ws(unsigned* ctr) {
    int i = blockIdx.x * blockDim.x + threadIdx.x;
    if (i < CTR_WORDS) ctr[i] = 0u;
}

// ---------------- main persistent kernel --------------------------------
__global__ void __launch_bounds__(BT, 2)
lee_lstm(const float* __restrict__ x,  const float* __restrict__ Wi,
         const float* __restrict__ Wh, const float* __restrict__ bia,
         const float* __restrict__ h0, const float* __restrict__ c0,
         float* __restrict__ out, float* __restrict__ ws) {
    unsigned* ctr = (unsigned*)ws;
    float* Wt = ws + WT_OFFSET;       // Wt[c][k], c-major, stride KTOT (6.3MB)

    const int tid = threadIdx.x;
    const int bid = blockIdx.x;
    const int grpid = bid & 7;        // XCD group (round-robin dispatch)

    __shared__ float2 red[BT];        // split-K reduction
    __shared__ float  gin[8][64];     // gate pre-activations for this block
    __shared__ float  zl[8][64];      // lee outputs

    // ---- phase 0: transpose+fuse weights (sc1 write-through -> L3)
    {
        int g  = bid * BT + tid;      // 0..131071
        int c  = g & (GAT - 1);
        int kb = (g >> 11) * 12;      // 64 k-groups * 12 = 768
        float* dst = Wt + c * KTOT + kb;
#pragma unroll
        for (int j = 0; j < 12; ++j) {
            int k = kb + j;
            float w = (k < INP) ? Wi[k * GAT + c] : Wh[(k - INP) * GAT + c];
            st_f32_sc(dst + j, w);
        }
    }
    bar_arrive(ctr, 0, grpid);
    bar_wait(ctr, 0);                 // Wt ready everywhere

    // ---- per-thread roles
    const int kh = tid >> 8;          // split-K half: 0/1
    const int t8 = tid & 255;
    const int ci = t8 & 7;            // 0..7 -> (gate type, hd parity)
    const int sq = t8 >> 3;           // 0..31 -> samples {sq, sq+32}
    const int gt = ci >> 1;           // 0:i 1:f 2:g 3:o
    const int hdq = 2 * bid + (ci & 1);
    const int col = gt * HID + hdq;
    const float* wrow = Wt + col * KTOT;
    const float bias  = bia[col];
    const int s0 = sq, s1 = sq + 32;

    // update-phase roles (threads 0..127): (hd_i, sample)
    const int uhd_i = tid >> 6;       // 0/1 when tid<128
    const int us    = tid & 63;
    const int uhd   = 2 * bid + uhd_i;
    float creg = 0.0f;
    if (tid < 128) creg = c0[us * HID + uhd];

    float accA = 0.0f, accB = 0.0f;
    // x-part for t=0 (k in [kh*128, kh*128+128))
    {
        const float4* wp = (const float4*)(wrow + kh * 128);
        const float4* xa = (const float4*)(x + s0 * (SEQ * INP) + kh * 128);
        const float4* xb = (const float4*)(x + s1 * (SEQ * INP) + kh * 128);
#pragma unroll 4
        for (int i = 0; i < 32; ++i) fma8(wp[i], xa[i], xb[i], accA, accB);
    }

    for (int t = 0; t < SEQ; ++t) {
        if (t > 0) bar_wait(ctr, t);  // h_{t-1} visible device-wide

        // ---- h-part GEMM (k in [kh*256, kh*256+256) of h)
        {
            const float4* wq = (const float4*)(wrow + INP + kh * 256);
            const float* hA = (t == 0) ? (h0 + s0 * HID)
                                       : (out + s0 * (SEQ * HID) + (t - 1) * HID);
            const float* hB = (t == 0) ? (h0 + s1 * HID)
                                       : (out + s1 * (SEQ * HID) + (t - 1) * HID);
            const float4* ha = (const float4*)(hA + kh * 256);
            const float4* hb = (const float4*)(hB + kh * 256);
#pragma unroll 8
            for (int i = 0; i < 64; ++i) fma8(wq[i], ha[i], hb[i], accA, accB);
        }

        // ---- split-K reduce + bias
        red[tid] = make_float2(accA, accB);
        __syncthreads();
        if (tid < 256) {
            float2 o = red[tid + 256];
            gin[ci][sq]      = accA + o.x + bias;
            gin[ci][sq + 32] = accB + o.y + bias;
        }
        __syncthreads();

        // ---- lee on all 512 gate elements (wave-uniform gate type)
        {
            int lci = tid >> 6;       // 0..7, uniform per wave
            int ls  = tid & 63;
            float gv = gin[lci][ls];
            float zres = (lci == 4 || lci == 5) ? lee<true>(gv) : lee<false>(gv);
            zl[lci][ls] = zres;
        }
        __syncthreads();

        // ---- cell/hidden update (threads 0..127, c in registers)
        if (tid < 128) {
            float iv = zl[0 + uhd_i][us];
            float fv = zl[2 + uhd_i][us];
            float gv = zl[4 + uhd_i][us];
            float ov = zl[6 + uhd_i][us];
            float cn = fmaf(fv, creg, iv * gv);
            creg = cn;
            float hn = ov * lee<true>(cn);
            st_f32_sc(out + us * (SEQ * HID) + t * HID + uhd, hn);  // write-through
            if (t == SEQ - 1) {
                st_f32_sc(out + OUT_MAIN + us * HID + uhd, hn);               // ht
                st_f32_sc(out + OUT_MAIN + BSZ * HID + us * HID + uhd, cn);   // ct
            }
        }
        bar_arrive(ctr, t + 1, grpid);

        // ---- overlap barrier latency: x@Wi partial for step t+1 (no h dep)
        if (t < SEQ - 1) {
            const float4* wp = (const float4*)(wrow + kh * 128);
            const float4* xa = (const float4*)(x + s0 * (SEQ * INP) + (t + 1) * INP + kh * 128);
            const float4* xb = (const float4*)(x + s1 * (SEQ * INP) + (t + 1) * INP + kh * 128);
            accA = 0.0f; accB = 0.0f;
#pragma unroll 4
            for (int i = 0; i < 32; ++i) fma8(wp[i], xa[i], xb[i], accA, accB);
        }
    }
}

extern "C" void kernel_launch(void* const* d_in, const int* in_sizes, int n_in,
                              void* d_out, int out_size, void* d_ws, size_t ws_size,
                              hipStream_t stream) {
    (void)in_sizes; (void)n_in; (void)out_size; (void)ws_size;
    const float* x  = (const float*)d_in[0];
    const float* Wi = (const float*)d_in[1];
    const float* Wh = (const float*)d_in[2];
    const float* b  = (const float*)d_in[3];
    const float* h0 = (const float*)d_in[4];
    const float* c0 = (const float*)d_in[5];
    float* out = (float*)d_out;
    float* ws  = (float*)d_ws;

    hipLaunchKernelGGL(zero_ws, dim3((CTR_WORDS + 511) / 512), dim3(512), 0, stream,
                       (unsigned*)d_ws);

    void* args[8];
    args[0] = (void*)&x;  args[1] = (void*)&Wi; args[2] = (void*)&Wh; args[3] = (void*)&b;
    args[4] = (void*)&h0; args[5] = (void*)&c0; args[6] = (void*)&out; args[7] = (void*)&ws;
    hipLaunchCooperativeKernel(reinterpret_cast<const void*>(lee_lstm),
                               dim3(NB), dim3(BT), args, 0, stream);
}

// Round 3
// 16296.750 us; speedup vs baseline: 2.5814x; 1.3700x over previous
//
#include <hip/hip_runtime.h>
#include <math.h>

// ChaoticLSTM (Lee-oscillator LSTM) on MI355X.
// BS=64, S=512, I=256, H=512, fp32. out = [output(64*512*512) | ht(64*512) | ct(64*512)].
//
// Persistent cooperative kernel: 256 blocks x 512 threads, one block per CU.
// Block b owns h-dims {2b, 2b+1} for ALL 64 samples; cell state c lives in
// registers (threads 0..127). h_t is exchanged via d_out (written anyway).
//
// Round-3: weights live in LDS (loaded once; immune to the per-step acquire
// buffer_inv), and the lee loop is ROLLED to keep the step-loop body well
// under the 32KB I-cache (round 1/2 floor was consistent with I-fetch thrash).

#define NB   256
#define BT   512
#define BSZ  64
#define SEQ  512
#define INP  256
#define HID  512
#define GAT  2048          // 4*HID
#define KTOT 768           // INP+HID
#define OUT_MAIN (BSZ*SEQ*HID)

#define SLOT_STRIDE 544    // uints per barrier slot (8 grp + 1 glob, 128B padded)
#define N_SLOTS     512    // slot t = "h_t visible"
#define CTR_WORDS   (N_SLOTS * SLOT_STRIDE)

// ---------------- fast activations -------------------------------------
__device__ __forceinline__ float rcp_f(float a) { return __builtin_amdgcn_rcpf(a); }
__device__ __forceinline__ float sigm_f(float a) {
    return rcp_f(1.0f + __expf(-a));
}
__device__ __forceinline__ float tanh_f(float a) {
    return 1.0f - 2.0f * rcp_f(__expf(2.0f * a) + 1.0f);
}

template <bool TANH>
__device__ __forceinline__ float lee(float xg) {
    float w   = TANH ? tanh_f(xg) : sigm_f(xg);
    float dec = __expf(-50.0f * xg * xg);
    float hx  = 0.5f * xg;
    float u = 0.0f, v = 0.0f, z = 0.0f;
#pragma unroll 1
    for (int i = 0; i < 25; ++i) {
        float tz = fmaf(-0.5f, z, hx);
        float s6 = 0.6f * (u + v);
        float au = tz + s6;
        float av = tz - s6;
        u = TANH ? tanh_f(au) : sigm_f(au);
        v = TANH ? tanh_f(av) : sigm_f(av);
        z = fmaf(u - v, dec, w);
    }
    return z;
}

// ---------------- sc0/sc1 write-through store ---------------------------
__device__ __forceinline__ void st_f32_sc(float* p, float v) {
    asm volatile("global_store_dword %0, %1, off sc0 sc1" :: "v"(p), "v"(v) : "memory");
}

// ---------------- two-level grid barrier --------------------------------
__device__ __forceinline__ void bar_arrive(unsigned* ctr, int slot, int g) {
    asm volatile("s_waitcnt vmcnt(0)" ::: "memory");  // per-wave: sc1 stores done
    __syncthreads();                                   // all waves drained
    if (threadIdx.x == 0) {
        unsigned* grp  = ctr + slot * SLOT_STRIDE + g * 32;
        unsigned* glob = ctr + slot * SLOT_STRIDE + 256;
        if (__hip_atomic_fetch_add(grp, 1u, __ATOMIC_RELAXED,
                                   __HIP_MEMORY_SCOPE_AGENT) == 31u)
            __hip_atomic_fetch_add(glob, 1u, __ATOMIC_RELAXED,
                                   __HIP_MEMORY_SCOPE_AGENT);
    }
}
__device__ __forceinline__ void bar_wait(unsigned* ctr, int slot) {
    if (threadIdx.x == 0) {
        unsigned* glob = ctr + slot * SLOT_STRIDE + 256;
        while (__hip_atomic_load(glob, __ATOMIC_RELAXED,
                                 __HIP_MEMORY_SCOPE_AGENT) < 8u)
            __builtin_amdgcn_s_sleep(1);
    }
    __syncthreads();
    __builtin_amdgcn_fence(__ATOMIC_ACQUIRE, "agent");  // buffer_inv only
}

__device__ __forceinline__ void fma8(const float4& w, const float4& a, const float4& b,
                                     float& A, float& B) {
    A = fmaf(w.x, a.x, A); A = fmaf(w.y, a.y, A);
    A = fmaf(w.z, a.z, A); A = fmaf(w.w, a.w, A);
    B = fmaf(w.x, b.x, B); B = fmaf(w.y, b.y, B);
    B = fmaf(w.z, b.z, B); B = fmaf(w.w, b.w, B);
}

// ---------------- prologue: zero barrier counters ------------------------
__global__ void zero_ws(unsigned* ctr) {
    int i = blockIdx.x * blockDim.x + threadIdx.x;
    if (i < CTR_WORDS) ctr[i] = 0u;
}

// ---------------- main persistent kernel --------------------------------
__global__ void __launch_bounds__(BT, 2)
lee_lstm(const float* __restrict__ x,  const float* __restrict__ Wi,
         const float* __restrict__ Wh, const float* __restrict__ bia,
         const float* __restrict__ h0, const float* __restrict__ c0,
         float* __restrict__ out, float* __restrict__ ws) {
    unsigned* ctr = (unsigned*)ws;

    const int tid = threadIdx.x;
    const int bid = blockIdx.x;
    const int grpid = bid & 7;

    __shared__ float  w8[8][772];     // 8 gate-cols x 768 fused-k (+4 pad: bank-safe)
    __shared__ float2 red[BT];        // split-K reduction
    __shared__ float  gin[8][64];     // gate pre-activations
    __shared__ float  zl[8][64];      // lee outputs

    // ---- load this block's 8 weight columns into LDS (once) -------------
    {
        int wci  = tid >> 6;          // 0..7 (wave-uniform)
        int lane = tid & 63;
        int col  = (wci >> 1) * HID + 2 * bid + (wci & 1);
#pragma unroll 1
        for (int j = 0; j < 12; ++j) {
            int k = lane + 64 * j;    // 0..767 fused k
            float wv = (k < INP) ? Wi[k * GAT + col] : Wh[(k - INP) * GAT + col];
            w8[wci][k] = wv;
        }
    }
    __syncthreads();

    // ---- per-thread roles
    const int kh = tid >> 8;          // split-K half: 0/1
    const int t8 = tid & 255;
    const int ci = t8 & 7;            // (gate type, hd parity)
    const int sq = t8 >> 3;           // samples {sq, sq+32}
    const int gt = ci >> 1;
    const int hdq = 2 * bid + (ci & 1);
    const int col = gt * HID + hdq;
    const float bias = bia[col];
    const int s0 = sq, s1 = sq + 32;

    const float4* wx = (const float4*)(&w8[ci][kh * 128]);        // x-part weights
    const float4* wq = (const float4*)(&w8[ci][INP + kh * 256]);  // h-part weights

    // update-phase roles (threads 0..127)
    const int uhd_i = tid >> 6;
    const int us    = tid & 63;
    const int uhd   = 2 * bid + uhd_i;
    float creg = 0.0f;
    if (tid < 128) creg = c0[us * HID + uhd];

    float accA = 0.0f, accB = 0.0f;
    {   // x-part for t=0
        const float4* xa = (const float4*)(x + s0 * (SEQ * INP) + kh * 128);
        const float4* xb = (const float4*)(x + s1 * (SEQ * INP) + kh * 128);
#pragma unroll 4
        for (int i = 0; i < 32; ++i) fma8(wx[i], xa[i], xb[i], accA, accB);
    }

    for (int t = 0; t < SEQ; ++t) {
        if (t > 0) bar_wait(ctr, t - 1);   // h_{t-1} visible device-wide

        // ---- h-part GEMM (weights from LDS, h from global/L2)
        {
            const float* hA = (t == 0) ? (h0 + s0 * HID)
                                       : (out + s0 * (SEQ * HID) + (t - 1) * HID);
            const float* hB = (t == 0) ? (h0 + s1 * HID)
                                       : (out + s1 * (SEQ * HID) + (t - 1) * HID);
            const float4* ha = (const float4*)(hA + kh * 256);
            const float4* hb = (const float4*)(hB + kh * 256);
#pragma unroll 8
            for (int i = 0; i < 64; ++i) fma8(wq[i], ha[i], hb[i], accA, accB);
        }

        // ---- split-K reduce + bias
        red[tid] = make_float2(accA, accB);
        __syncthreads();
        if (tid < 256) {
            float2 o = red[tid + 256];
            gin[ci][sq]      = accA + o.x + bias;
            gin[ci][sq + 32] = accB + o.y + bias;
        }
        __syncthreads();

        // ---- lee on all 512 gate elements (wave-uniform gate type)
        {
            int lci = tid >> 6;
            int ls  = tid & 63;
            float gv = gin[lci][ls];
            float zres = (lci == 4 || lci == 5) ? lee<true>(gv) : lee<false>(gv);
            zl[lci][ls] = zres;
        }
        __syncthreads();

        // ---- cell/hidden update (threads 0..127, c in registers)
        if (tid < 128) {
            float iv = zl[0 + uhd_i][us];
            float fv = zl[2 + uhd_i][us];
            float gv = zl[4 + uhd_i][us];
            float ov = zl[6 + uhd_i][us];
            float cn = fmaf(fv, creg, iv * gv);
            creg = cn;
            float hn = ov * lee<true>(cn);
            st_f32_sc(out + us * (SEQ * HID) + t * HID + uhd, hn);
            if (t == SEQ - 1) {
                st_f32_sc(out + OUT_MAIN + us * HID + uhd, hn);               // ht
                st_f32_sc(out + OUT_MAIN + BSZ * HID + us * HID + uhd, cn);   // ct
            }
        }
        bar_arrive(ctr, t, grpid);

        // ---- overlap barrier latency: x@Wi partial for step t+1 (no h dep)
        if (t < SEQ - 1) {
            const float4* xa = (const float4*)(x + s0 * (SEQ * INP) + (t + 1) * INP + kh * 128);
            const float4* xb = (const float4*)(x + s1 * (SEQ * INP) + (t + 1) * INP + kh * 128);
            accA = 0.0f; accB = 0.0f;
#pragma unroll 4
            for (int i = 0; i < 32; ++i) fma8(wx[i], xa[i], xb[i], accA, accB);
        }
    }
}

extern "C" void kernel_launch(void* const* d_in, const int* in_sizes, int n_in,
                              void* d_out, int out_size, void* d_ws, size_t ws_size,
                              hipStream_t stream) {
    (void)in_sizes; (void)n_in; (void)out_size; (void)ws_size;
    const float* x  = (const float*)d_in[0];
    const float* Wi = (const float*)d_in[1];
    const float* Wh = (const float*)d_in[2];
    const float* b  = (const float*)d_in[3];
    const float* h0 = (const float*)d_in[4];
    const float* c0 = (const float*)d_in[5];
    float* out = (float*)d_out;
    float* ws  = (float*)d_ws;

    hipLaunchKernelGGL(zero_ws, dim3((CTR_WORDS + 511) / 512), dim3(512), 0, stream,
                       (unsigned*)d_ws);

    void* args[8];
    args[0] = (void*)&x;  args[1] = (void*)&Wi; args[2] = (void*)&Wh; args[3] = (void*)&b;
    args[4] = (void*)&h0; args[5] = (void*)&c0; args[6] = (void*)&out; args[7] = (void*)&ws;
    hipLaunchCooperativeKernel(reinterpret_cast<const void*>(lee_lstm),
                               dim3(NB), dim3(BT), args, 0, stream);
}